// Round 3
// baseline (586.394 us; speedup 1.0000x reference)
//
#include <hip/hip_runtime.h>

#define R 256
#define T 32

#define TROWS 8         // out rows per wave tile
#define HC 34           // hidden cols (32 + 2 halo) — EVEN
#define HRR 10          // hidden rows per wave tile (8 + 2 halo)
#define HSTR 34         // hidden row stride (words)
#define GP 356          // G-plane stride; 356 %32 == 4 (R21-proven base pattern)
#define WSLICE (9 * GP) // per-wave G slice: 3204 words = 12816 B
#define NPX (HRR * HC)  // 340 hidden px per wave tile
#define NPAIR (NPX / 2) // 170 pairs; slots 0..1 full, slot 2: lane < 42

typedef float v2f __attribute__((ext_vector_type(2)));
#define FMA2(a, b, c) __builtin_elementwise_fma((a), (b), (c))

// ---------------------------------------------------------------------------
// Kernel A (R16 — 512-thr bq-major, yt staged once; ~9 us, HBM-roofline)
// ---------------------------------------------------------------------------
__global__ __launch_bounds__(512) void einsum_kernel(
    const float* __restrict__ yt, const float* __restrict__ Ht,
    float* __restrict__ x) {
  const int bq  = blockIdx.x >> 6;
  const int yy  = blockIdx.x & 63;
  const int b0  = bq * 8;
  const int tid = threadIdx.x;
  const int q   = tid & 255;
  const int rhh = tid >> 8;
  const int q4  = q >> 2;

  __shared__ float yts[8 * 32 * 64];

#pragma unroll
  for (int i = 0; i < 8; ++i) {
    int f4  = tid + i * 512;
    int b_l = f4 >> 9;
    int t   = (f4 >> 4) & 31;
    int xx4 = f4 & 15;
    float4 v = *(const float4*)(yt + (((size_t)(b0 + b_l) * T + t) * 64 + yy) * 64 + xx4 * 4);
    *(float4*)(yts + f4 * 4) = v;
  }
  __syncthreads();

#pragma unroll
  for (int rr = 0; rr < 2; ++rr) {
    const int p = yy * 4 + rhh * 2 + rr;
    float ht[T];
#pragma unroll
    for (int t = 0; t < T; ++t) ht[t] = Ht[((size_t)t * R + p) * R + q];

#pragma unroll
    for (int b_l = 0; b_l < 8; ++b_l) {
      const float* ys = yts + b_l * 2048 + q4;
      float acc = 0.f;
#pragma unroll
      for (int t = 0; t < T; ++t) acc += ht[t] * ys[t * 64];
      x[((size_t)(b0 + b_l) * R + p) * R + q] = acc;
    }
  }
}

// ---------------------------------------------------------------------------
// Kernel B: fused Conv(1->32,3x3) -> ReLU -> Conv(32->1,3x3), SAME.
// TAP-CONTRACTION restructure (R3): out[o] = b2 + sum_k G_k[o+dk] with
// G_k[p] = sum_ch W2[ch,k]*relu(conv1[ch,p]). Each lane streams all 32
// channels through registers (as before) but contracts against W2
// in-register and stores only 9 G-planes — LDS writes /3, reads /5, ONE
// write->read phase instead of 8 (R2 showed the 8 per-cg LDS round-trips
// were the wall: occupancy +75% -> dur flat). W2 index is now lane-uniform
// -> s_loads. No cl-split, no shuffle reduce; all lanes write output.
// R0 POST-MORTEM: bank micro-swizzles are counterproductive; keep %32==4
// plane strides and post-relu cndmask zeroing. Keep every index
// compile-time constant (runtime indexing spills catastrophically).
// ---------------------------------------------------------------------------
template <bool EDGE>
__device__ __forceinline__ void conv_tile(
    const float* __restrict__ xb, int ty0, int ox0, int lane, float* gw,
    const float* __restrict__ W1, const float* __restrict__ b1,
    const float* __restrict__ W2, const float* __restrict__ b2,
    float* __restrict__ outp) {
  v2f  patch2[3][9];
  int  sw[3];
  bool oob[6];
  const bool slot2 = (lane < NPAIR - 2 * 64);   // 42 lanes
#pragma unroll
  for (int it = 0; it < 3; ++it) {
    int pi = lane + it * 64;
    bool act = (it < 2) || slot2;
    int px0 = 2 * pi;
    int hy  = act ? (px0 / HC) : 0;
    int hx0 = act ? (px0 % HC) : 0;       // even
    sw[it] = hy * HSTR + hx0;             // even -> b64-aligned store
    int ghy = ty0 - 1 + hy;
    int ghx0 = ox0 - 1 + hx0;
    bool rowok = (ghy >= 0) & (ghy < R);
    oob[2 * it]     = !(rowok & (ghx0 >= 0) & (ghx0 < R));
    oob[2 * it + 1] = !(rowok & (ghx0 + 1 >= 0) & (ghx0 + 1 < R));
#pragma unroll
    for (int ky = 0; ky < 3; ++ky) {
      const int gy  = ty0 - 2 + hy + ky;
      const int gx0 = ox0 - 2 + hx0;
      v2f fa, fb;
      if (EDGE) {
        float xv[4];
#pragma unroll
        for (int c = 0; c < 4; ++c) {
          int gx = gx0 + c;
          bool ok = act & (gy >= 0) & (gy < R) & (gx >= 0) & (gx < R);
          xv[c] = ok ? xb[gy * R + gx] : 0.f;
        }
        fa = (v2f){xv[0], xv[1]};
        fb = (v2f){xv[2], xv[3]};
      } else {
        const float* xp = xb + gy * R + gx0;
        fa = act ? *(const v2f*)(xp)     : (v2f){0.f, 0.f};
        fb = act ? *(const v2f*)(xp + 2) : (v2f){0.f, 0.f};
      }
      patch2[it][3 * ky + 0] = fa;
      patch2[it][3 * ky + 1] = (v2f){fa.y, fb.x};
      patch2[it][3 * ky + 2] = fb;
    }
  }

  // ---- stream 32 channels: conv1+relu in regs, contract into 9 G-planes --
  v2f G[9][3];
#pragma unroll
  for (int k = 0; k < 9; ++k)
#pragma unroll
    for (int s = 0; s < 3; ++s) G[k][s] = (v2f){0.f, 0.f};

#pragma unroll
  for (int ch = 0; ch < 32; ++ch) {
    const float bias = b1[ch];
    v2f h[3];
#pragma unroll
    for (int s = 0; s < 3; ++s) h[s] = (v2f){bias, bias};
#pragma unroll
    for (int k = 0; k < 9; ++k) {
      const float w = W1[ch * 9 + k];
      const v2f wv = {w, w};
#pragma unroll
      for (int s = 0; s < 3; ++s) h[s] = FMA2(wv, patch2[s][k], h[s]);
    }
    const v2f z = {0.f, 0.f};
#pragma unroll
    for (int s = 0; s < 3; ++s) h[s] = __builtin_elementwise_max(h[s], z);
    if (EDGE) {
#pragma unroll
      for (int s = 0; s < 3; ++s) {
        if (oob[2 * s])     h[s].x = 0.f;
        if (oob[2 * s + 1]) h[s].y = 0.f;
      }
    }
#pragma unroll
    for (int k = 0; k < 9; ++k) {
      const float w2v = W2[ch * 9 + k];   // lane-uniform -> s_load
      const v2f wp = {w2v, w2v};
#pragma unroll
      for (int s = 0; s < 3; ++s) G[k][s] = FMA2(wp, h[s], G[k][s]);
    }
  }

  // ---- single LDS phase: store 9 G-planes ----
#pragma unroll
  for (int k = 0; k < 9; ++k) {
    float* gp = gw + k * GP;
    *(v2f*)(gp + sw[0]) = G[k][0];
    *(v2f*)(gp + sw[1]) = G[k][1];
    if (slot2) *(v2f*)(gp + sw[2]) = G[k][2];
  }

  // ---- gather: out[row,col..col+1] = b2 + sum_{dy,dx} G_{dy,dx}[row+dy,col+dx]
  const float bias2 = b2[0];
  const int oy  = lane >> 4;        // 0..3
  const int col = 2 * (lane & 15);  // 0,2,..,30
#pragma unroll
  for (int half = 0; half < 2; ++half) {
    const int row = oy + 4 * half;
    v2f a = {bias2, bias2};
#pragma unroll
    for (int dy = 0; dy < 3; ++dy) {
      const float* gr = gw + (row + dy) * HSTR + col;
      a += *(const v2f*)(gr + (3 * dy + 0) * GP);           // dx=0 (aligned)
      v2f m;                                                 // dx=1 (odd)
      m.x = gr[(3 * dy + 1) * GP + 1];
      m.y = gr[(3 * dy + 1) * GP + 2];
      a += m;
      a += *(const v2f*)(gr + (3 * dy + 2) * GP + 2);       // dx=2 (aligned)
    }
    *(v2f*)(outp + (size_t)(ty0 + row) * R + ox0 + col) = a;
  }
}

__global__ __launch_bounds__(128, 3) void conv_fused_kernel(
    const float* __restrict__ x, const float* __restrict__ W1,
    const float* __restrict__ b1, const float* __restrict__ W2,
    const float* __restrict__ b2, float* __restrict__ out) {
  __shared__ float hs[2 * WSLICE];   // 25632 B -> 6 blocks/CU = 12 waves

  const int tid  = threadIdx.x;
  const int lane = tid & 63;
  const int wv   = tid >> 6;                 // 0..1
  const int b    = blockIdx.x >> 7;
  const int tile = blockIdx.x & 127;         // 16 row-blocks x 8 col-blocks
  const int ty0  = (tile >> 3) * 16 + wv * TROWS;
  const int ox0  = (tile & 7) * 32;
  const float* xb   = x + (size_t)b * R * R;
  float*       outp = out + (size_t)b * R * R;
  float*       gsw  = hs + wv * WSLICE;

  const bool edge = (ty0 == 0) | (ty0 == R - TROWS) | (ox0 == 0) | (ox0 == R - 32);
  if (edge)
    conv_tile<true>(xb, ty0, ox0, lane, gsw, W1, b1, W2, b2, outp);
  else
    conv_tile<false>(xb, ty0, ox0, lane, gsw, W1, b1, W2, b2, outp);
}

// ---------------------------------------------------------------------------
extern "C" void kernel_launch(void* const* d_in, const int* in_sizes, int n_in,
                              void* d_out, int out_size, void* d_ws, size_t ws_size,
                              hipStream_t stream) {
  const float* yt = (const float*)d_in[0];  // (32,32,64,64)
  const float* Ht = (const float*)d_in[1];  // (32,256,256)
  const float* W1 = (const float*)d_in[2];  // (32,1,3,3)
  const float* b1 = (const float*)d_in[3];  // (32,)
  const float* W2 = (const float*)d_in[4];  // (1,32,3,3)
  const float* b2 = (const float*)d_in[5];  // (1,)
  float* outp = (float*)d_out;              // (32,1,256,256)
  float* x    = (float*)d_ws;               // 8 MB scratch

  einsum_kernel<<<256, 512, 0, stream>>>(yt, Ht, x);
  conv_fused_kernel<<<4096, 128, 0, stream>>>(x, W1, b1, W2, b2, outp);
}

// Round 4
// 223.344 us; speedup vs baseline: 2.6255x; 2.6255x over previous
//
#include <hip/hip_runtime.h>

#define R 256
#define T 32

#define TROWS 8         // out rows per wave tile
#define HC 34           // hidden cols (32 + 2 halo) — EVEN
#define HRR 10          // hidden rows per wave tile (8 + 2 halo)
#define HSTR 34         // hidden row stride (words)
#define GP 356          // G-plane stride; 356 %32 == 4 (R21-proven base pattern)
#define WSLICE (9 * GP) // per-wave G slice: 3204 words = 12816 B
#define NPX (HRR * HC)  // 340 hidden px per wave tile
#define NPAIR (NPX / 2) // 170 pairs; slots 0..1 full, slot 2: lane < 42

typedef float v2f __attribute__((ext_vector_type(2)));
#define FMA2(a, b, c) __builtin_elementwise_fma((a), (b), (c))

// ---------------------------------------------------------------------------
// Kernel A (R16 — 512-thr bq-major, yt staged once; ~9 us, HBM-roofline)
// ---------------------------------------------------------------------------
__global__ __launch_bounds__(512) void einsum_kernel(
    const float* __restrict__ yt, const float* __restrict__ Ht,
    float* __restrict__ x) {
  const int bq  = blockIdx.x >> 6;
  const int yy  = blockIdx.x & 63;
  const int b0  = bq * 8;
  const int tid = threadIdx.x;
  const int q   = tid & 255;
  const int rhh = tid >> 8;
  const int q4  = q >> 2;

  __shared__ float yts[8 * 32 * 64];

#pragma unroll
  for (int i = 0; i < 8; ++i) {
    int f4  = tid + i * 512;
    int b_l = f4 >> 9;
    int t   = (f4 >> 4) & 31;
    int xx4 = f4 & 15;
    float4 v = *(const float4*)(yt + (((size_t)(b0 + b_l) * T + t) * 64 + yy) * 64 + xx4 * 4);
    *(float4*)(yts + f4 * 4) = v;
  }
  __syncthreads();

#pragma unroll
  for (int rr = 0; rr < 2; ++rr) {
    const int p = yy * 4 + rhh * 2 + rr;
    float ht[T];
#pragma unroll
    for (int t = 0; t < T; ++t) ht[t] = Ht[((size_t)t * R + p) * R + q];

#pragma unroll
    for (int b_l = 0; b_l < 8; ++b_l) {
      const float* ys = yts + b_l * 2048 + q4;
      float acc = 0.f;
#pragma unroll
      for (int t = 0; t < T; ++t) acc += ht[t] * ys[t * 64];
      x[((size_t)(b0 + b_l) * R + p) * R + q] = acc;
    }
  }
}

// ---------------------------------------------------------------------------
// Kernel B: fused Conv(1->32,3x3) -> ReLU -> Conv(32->1,3x3), SAME.
// TAP-CONTRACTION: out[o] = b2 + sum_k G_k[o+dk] with
// G_k[p] = sum_ch W2[ch,k]*relu(conv1[ch,p]). Each lane streams all 32
// channels through registers, contracts against W2 in-register, stores only
// 9 G-planes — LDS writes /3, reads /5, ONE write->read phase instead of 8
// (R2: 8 per-cg LDS round-trips were the wall; occupancy +75% -> dur flat).
// R3 POST-MORTEM: __launch_bounds__(128,3) forced VGPR cap 84 < ~130 live
// -> 1.4 GB scratch spill, 528 us. NEVER set the min-occupancy bound here;
// body needs ~150-190 VGPR. Bank conflicts with this structure: 196K (was
// 3.93M) — the restructure's conflict prediction verified.
// Keep every index compile-time constant (runtime indexing spills).
// ---------------------------------------------------------------------------
template <bool EDGE>
__device__ __forceinline__ void conv_tile(
    const float* __restrict__ xb, int ty0, int ox0, int lane, float* gw,
    const float* __restrict__ W1, const float* __restrict__ b1,
    const float* __restrict__ W2, const float* __restrict__ b2,
    float* __restrict__ outp) {
  v2f  patch2[3][9];
  int  sw[3];
  bool oob[6];
  const bool slot2 = (lane < NPAIR - 2 * 64);   // 42 lanes
#pragma unroll
  for (int it = 0; it < 3; ++it) {
    int pi = lane + it * 64;
    bool act = (it < 2) || slot2;
    int px0 = 2 * pi;
    int hy  = act ? (px0 / HC) : 0;
    int hx0 = act ? (px0 % HC) : 0;       // even
    sw[it] = hy * HSTR + hx0;             // even -> b64-aligned store
    int ghy = ty0 - 1 + hy;
    int ghx0 = ox0 - 1 + hx0;
    bool rowok = (ghy >= 0) & (ghy < R);
    oob[2 * it]     = !(rowok & (ghx0 >= 0) & (ghx0 < R));
    oob[2 * it + 1] = !(rowok & (ghx0 + 1 >= 0) & (ghx0 + 1 < R));
#pragma unroll
    for (int ky = 0; ky < 3; ++ky) {
      const int gy  = ty0 - 2 + hy + ky;
      const int gx0 = ox0 - 2 + hx0;
      v2f fa, fb;
      if (EDGE) {
        float xv[4];
#pragma unroll
        for (int c = 0; c < 4; ++c) {
          int gx = gx0 + c;
          bool ok = act & (gy >= 0) & (gy < R) & (gx >= 0) & (gx < R);
          xv[c] = ok ? xb[gy * R + gx] : 0.f;
        }
        fa = (v2f){xv[0], xv[1]};
        fb = (v2f){xv[2], xv[3]};
      } else {
        const float* xp = xb + gy * R + gx0;
        fa = act ? *(const v2f*)(xp)     : (v2f){0.f, 0.f};
        fb = act ? *(const v2f*)(xp + 2) : (v2f){0.f, 0.f};
      }
      patch2[it][3 * ky + 0] = fa;
      patch2[it][3 * ky + 1] = (v2f){fa.y, fb.x};
      patch2[it][3 * ky + 2] = fb;
    }
  }

  // ---- stream 32 channels: conv1+relu in regs, contract into 9 G-planes --
  v2f G[9][3];
#pragma unroll
  for (int k = 0; k < 9; ++k)
#pragma unroll
    for (int s = 0; s < 3; ++s) G[k][s] = (v2f){0.f, 0.f};

#pragma unroll
  for (int ch = 0; ch < 32; ++ch) {
    const float bias = b1[ch];
    v2f h[3];
#pragma unroll
    for (int s = 0; s < 3; ++s) h[s] = (v2f){bias, bias};
#pragma unroll
    for (int k = 0; k < 9; ++k) {
      const float w = W1[ch * 9 + k];
      const v2f wv = {w, w};
#pragma unroll
      for (int s = 0; s < 3; ++s) h[s] = FMA2(wv, patch2[s][k], h[s]);
    }
    const v2f z = {0.f, 0.f};
#pragma unroll
    for (int s = 0; s < 3; ++s) h[s] = __builtin_elementwise_max(h[s], z);
    if (EDGE) {
#pragma unroll
      for (int s = 0; s < 3; ++s) {
        if (oob[2 * s])     h[s].x = 0.f;
        if (oob[2 * s + 1]) h[s].y = 0.f;
      }
    }
#pragma unroll
    for (int k = 0; k < 9; ++k) {
      const float w2v = W2[ch * 9 + k];   // lane-uniform -> s_load
      const v2f wp = {w2v, w2v};
#pragma unroll
      for (int s = 0; s < 3; ++s) G[k][s] = FMA2(wp, h[s], G[k][s]);
    }
  }

  // ---- single LDS phase: store 9 G-planes ----
#pragma unroll
  for (int k = 0; k < 9; ++k) {
    float* gp = gw + k * GP;
    *(v2f*)(gp + sw[0]) = G[k][0];
    *(v2f*)(gp + sw[1]) = G[k][1];
    if (slot2) *(v2f*)(gp + sw[2]) = G[k][2];
  }

  // ---- gather: out[row,col..col+1] = b2 + sum_{dy,dx} G_{dy,dx}[row+dy,col+dx]
  const float bias2 = b2[0];
  const int oy  = lane >> 4;        // 0..3
  const int col = 2 * (lane & 15);  // 0,2,..,30
#pragma unroll
  for (int half = 0; half < 2; ++half) {
    const int row = oy + 4 * half;
    v2f a = {bias2, bias2};
#pragma unroll
    for (int dy = 0; dy < 3; ++dy) {
      const float* gr = gw + (row + dy) * HSTR + col;
      a += *(const v2f*)(gr + (3 * dy + 0) * GP);           // dx=0 (aligned)
      v2f m;                                                 // dx=1 (odd)
      m.x = gr[(3 * dy + 1) * GP + 1];
      m.y = gr[(3 * dy + 1) * GP + 2];
      a += m;
      a += *(const v2f*)(gr + (3 * dy + 2) * GP + 2);       // dx=2 (aligned)
    }
    *(v2f*)(outp + (size_t)(ty0 + row) * R + ox0 + col) = a;
  }
}

__global__ __launch_bounds__(128) void conv_fused_kernel(
    const float* __restrict__ x, const float* __restrict__ W1,
    const float* __restrict__ b1, const float* __restrict__ W2,
    const float* __restrict__ b2, float* __restrict__ out) {
  __shared__ float hs[2 * WSLICE];   // 25632 B

  const int tid  = threadIdx.x;
  const int lane = tid & 63;
  const int wv   = tid >> 6;                 // 0..1
  const int b    = blockIdx.x >> 7;
  const int tile = blockIdx.x & 127;         // 16 row-blocks x 8 col-blocks
  const int ty0  = (tile >> 3) * 16 + wv * TROWS;
  const int ox0  = (tile & 7) * 32;
  const float* xb   = x + (size_t)b * R * R;
  float*       outp = out + (size_t)b * R * R;
  float*       gsw  = hs + wv * WSLICE;

  const bool edge = (ty0 == 0) | (ty0 == R - TROWS) | (ox0 == 0) | (ox0 == R - 32);
  if (edge)
    conv_tile<true>(xb, ty0, ox0, lane, gsw, W1, b1, W2, b2, outp);
  else
    conv_tile<false>(xb, ty0, ox0, lane, gsw, W1, b1, W2, b2, outp);
}

// ---------------------------------------------------------------------------
extern "C" void kernel_launch(void* const* d_in, const int* in_sizes, int n_in,
                              void* d_out, int out_size, void* d_ws, size_t ws_size,
                              hipStream_t stream) {
  const float* yt = (const float*)d_in[0];  // (32,32,64,64)
  const float* Ht = (const float*)d_in[1];  // (32,256,256)
  const float* W1 = (const float*)d_in[2];  // (32,1,3,3)
  const float* b1 = (const float*)d_in[3];  // (32,)
  const float* W2 = (const float*)d_in[4];  // (1,32,3,3)
  const float* b2 = (const float*)d_in[5];  // (1,)
  float* outp = (float*)d_out;              // (32,1,256,256)
  float* x    = (float*)d_ws;               // 8 MB scratch

  einsum_kernel<<<256, 512, 0, stream>>>(yt, Ht, x);
  conv_fused_kernel<<<4096, 128, 0, stream>>>(x, W1, b1, W2, b2, outp);
}